// Round 1
// 13444.788 us; speedup vs baseline: 1.6387x; 1.6387x over previous
//
#include <hip/hip_runtime.h>

#define B_ 128
#define T_ 256
#define H_ 512
#define O_ 256
#define X_ 768

typedef unsigned short u16;
typedef unsigned int u32;

#if __has_builtin(__builtin_amdgcn_exp2f)
#define EXP2(x) __builtin_amdgcn_exp2f(x)
#else
#define EXP2(x) exp2f(x)
#endif
#if __has_builtin(__builtin_amdgcn_rcpf)
#define RCPF(x) __builtin_amdgcn_rcpf(x)
#else
#define RCPF(x) (1.0f / (x))
#endif

#define LOG2E_F 1.4426950408889634f
#define TWOLOG2E_F 2.8853900817779268f

typedef __attribute__((ext_vector_type(8))) short short8;
typedef __attribute__((ext_vector_type(4))) float f32x4;

__device__ __forceinline__ float bf2f(u16 v) {
  union { u32 u; float f; } c; c.u = ((u32)v) << 16; return c.f;
}
__device__ __forceinline__ u16 f2bf(float f) {
  union { float f; u32 u; } c; c.f = f;
  return (u16)((c.u + 0x7FFFu + ((c.u >> 16) & 1u)) >> 16);
}
__device__ __forceinline__ float ftanh(float x) {
  x = fminf(fmaxf(x, -40.f), 40.f);
  float z = EXP2(x * TWOLOG2E_F);
  return (z - 1.0f) * RCPF(z + 1.0f);
}
__device__ __forceinline__ float fsigm(float x) {
  x = fminf(fmaxf(x, -40.f), 40.f);
  return RCPF(1.0f + EXP2(-x * LOG2E_F));
}

// ---- module-scope scratch ----
__device__ u16 g_hp[(size_t)B_ * T_ * H_];   // bf16 h_proj (33.5 MB)
__device__ u16 g_hb[(size_t)B_ * T_ * H_];   // bf16 copy of h (33.5 MB)
__device__ float g_sA[B_ * H_];
__device__ float g_sB[B_ * H_];
__device__ float g_u[B_ * H_];

// A-activation buffer for gate MFMAs, bf16 hi + lo residual.
// cols [0,768) = x = [y3 | c]; [768,1280) = s; [1280,1792) = r*s
#define AW 1792
__device__ u16 g_abh[(size_t)B_ * AW];
__device__ u16 g_abl[(size_t)B_ * AW];

// bf16 weight copies (k_step1 path, unchanged)
__device__ u16 cWy1[H_ * H_];
__device__ u16 cby1[H_];
__device__ u16 cWy2[H_ * H_];
__device__ u16 cby2[H_];
__device__ u16 cWy3[H_ * O_];
__device__ u16 cby3[O_];
__device__ u16 cWe1[2 * H_ * H_];
__device__ u16 cbe1[H_];
__device__ u16 cWe2[H_];
__device__ u16 cbr[H_];
__device__ u16 cbu[H_];

// pre-transposed bf16 gate weights: W^T[n][k], k-major contiguous (16B frags)
// W_BT: n in [0,512)=r cols, [512,1024)=u cols; k in [0,768)=Wx*, [768,1280)=Wh*
__device__ u16 W_BT[(size_t)1024 * 1280];
// W_CT: n in [0,512); k in [0,768)=Wxh, [768,1280)=Whh
__device__ u16 W_CT[(size_t)512 * 1280];

#define DEF_CONV(NAME, ARR, N)                                     \
  __global__ void conv_##NAME(const float* __restrict__ s) {       \
    int i = blockIdx.x * 256 + threadIdx.x;                        \
    if (i < (N)) ARR[i] = f2bf(s[i]);                              \
  }

DEF_CONV(Wy1, cWy1, H_ * H_)
DEF_CONV(by1, cby1, H_)
DEF_CONV(Wy2, cWy2, H_ * H_)
DEF_CONV(by2, cby2, H_)
DEF_CONV(Wy3, cWy3, H_ * O_)
DEF_CONV(by3, cby3, O_)
DEF_CONV(We1, cWe1, 2 * H_ * H_)
DEF_CONV(be1, cbe1, H_)
DEF_CONV(We2, cWe2, H_)
DEF_CONV(br, cbr, H_)
DEF_CONV(bu, cbu, H_)

__global__ void conv_h(const float* __restrict__ s) {
  size_t i = (size_t)blockIdx.x * 256 + threadIdx.x;
  g_hb[i] = f2bf(s[i]);
}

// transpose+pack gate weights: W_BT[n][k]
__global__ void conv_WBT(const float* __restrict__ Wxr, const float* __restrict__ Whr,
                         const float* __restrict__ Wxu, const float* __restrict__ Whu) {
  int idx = blockIdx.x * 256 + threadIdx.x;   // 1024 * 160 chunks of 8
  int n = idx / 160, kc = (idx - n * 160) * 8;
  int nn = (n < 512) ? n : n - 512;
  __align__(16) u16 tmp[8];
#pragma unroll
  for (int j = 0; j < 8; ++j) {
    int k = kc + j;
    float v;
    if (n < 512) v = (k < 768) ? Wxr[(size_t)k * H_ + nn] : Whr[(size_t)(k - 768) * H_ + nn];
    else         v = (k < 768) ? Wxu[(size_t)k * H_ + nn] : Whu[(size_t)(k - 768) * H_ + nn];
    tmp[j] = f2bf(v);
  }
  *(uint4*)(W_BT + (size_t)n * 1280 + kc) = *(const uint4*)tmp;
}

__global__ void conv_WCT(const float* __restrict__ Wxh, const float* __restrict__ Whh) {
  int idx = blockIdx.x * 256 + threadIdx.x;   // 512 * 160 chunks of 8
  int n = idx / 160, kc = (idx - n * 160) * 8;
  __align__(16) u16 tmp[8];
#pragma unroll
  for (int j = 0; j < 8; ++j) {
    int k = kc + j;
    float v = (k < 768) ? Wxh[(size_t)k * H_ + n] : Whh[(size_t)(k - 768) * H_ + n];
    tmp[j] = f2bf(v);
  }
  *(uint4*)(W_CT + (size_t)n * 1280 + kc) = *(const uint4*)tmp;
}

__global__ void init_kernel(const float* __restrict__ s0) {
  int g = blockIdx.x * blockDim.x + threadIdx.x;
  if (g < B_ * H_) {
    float v = s0[g];
    g_sA[g] = v;
    int b = g >> 9, n = g & 511;
    u16 hi = f2bf(v);
    g_abh[(size_t)b * AW + 768 + n] = hi;
    g_abl[(size_t)b * AW + 768 + n] = f2bf(v - bf2f(hi));
  }
}

// ---- h_proj = h @ We1[:H]  (fp32 in, bf16 out) ----
__global__ void __launch_bounds__(256) hproj_kernel(const float* __restrict__ hh,
                                                    const float* __restrict__ We1) {
  __shared__ float Ast[32][72];  // [k][m]
  __shared__ float Bs[32][72];   // [k][n]
  const int tid = threadIdx.x;
  const int tx = tid & 15, ty = tid >> 4;
  const int n0 = blockIdx.x << 6;
  const int m0 = blockIdx.y << 6;
  float acc[4][4] = {};
  for (int k0 = 0; k0 < H_; k0 += 32) {
    {
      int row = tid >> 2, kq = (tid & 3) << 3;
      const float* src = hh + (size_t)(m0 + row) * H_ + k0 + kq;
      float4 v0 = *(const float4*)src;
      float4 v1 = *(const float4*)(src + 4);
      Ast[kq + 0][row] = v0.x; Ast[kq + 1][row] = v0.y;
      Ast[kq + 2][row] = v0.z; Ast[kq + 3][row] = v0.w;
      Ast[kq + 4][row] = v1.x; Ast[kq + 5][row] = v1.y;
      Ast[kq + 6][row] = v1.z; Ast[kq + 7][row] = v1.w;
    }
    {
      int kr = tid >> 3, nq = (tid & 7) << 3;
      const float* src = We1 + (size_t)(k0 + kr) * H_ + n0 + nq;
      float4 v0 = *(const float4*)src;
      float4 v1 = *(const float4*)(src + 4);
      float* d = &Bs[kr][nq];
      d[0] = v0.x; d[1] = v0.y; d[2] = v0.z; d[3] = v0.w;
      d[4] = v1.x; d[5] = v1.y; d[6] = v1.z; d[7] = v1.w;
    }
    __syncthreads();
#pragma unroll
    for (int kk = 0; kk < 32; ++kk) {
      const float4 a4 = *(const float4*)&Ast[kk][ty << 2];
      const float4 b4 = *(const float4*)&Bs[kk][tx << 2];
      float av[4] = {a4.x, a4.y, a4.z, a4.w};
      float bv[4] = {b4.x, b4.y, b4.z, b4.w};
#pragma unroll
      for (int i = 0; i < 4; ++i)
#pragma unroll
        for (int j = 0; j < 4; ++j) acc[i][j] = fmaf(av[i], bv[j], acc[i][j]);
    }
    __syncthreads();
  }
#pragma unroll
  for (int i = 0; i < 4; ++i) {
    u16* dst = g_hp + (size_t)(m0 + ty * 4 + i) * H_ + n0 + tx * 4;
    u32 w0 = (u32)f2bf(acc[i][0]) | ((u32)f2bf(acc[i][1]) << 16);
    u32 w1 = (u32)f2bf(acc[i][2]) | ((u32)f2bf(acc[i][3]) << 16);
    *(u32*)dst = w0;
    *(u32*)(dst + 2) = w1;
  }
}

// unpack 8 bf16 (uint4) + fma against broadcast scalar
#define FMA8(pk, sk, A)                                          \
  {                                                              \
    u32 ww0 = pk.x, ww1 = pk.y, ww2 = pk.z, ww3 = pk.w;          \
    A[0] = fmaf(sk, bf2f((u16)(ww0 & 0xffffu)), A[0]);           \
    A[1] = fmaf(sk, bf2f((u16)(ww0 >> 16)), A[1]);               \
    A[2] = fmaf(sk, bf2f((u16)(ww1 & 0xffffu)), A[2]);           \
    A[3] = fmaf(sk, bf2f((u16)(ww1 >> 16)), A[3]);               \
    A[4] = fmaf(sk, bf2f((u16)(ww2 & 0xffffu)), A[4]);           \
    A[5] = fmaf(sk, bf2f((u16)(ww2 >> 16)), A[5]);               \
    A[6] = fmaf(sk, bf2f((u16)(ww3 & 0xffffu)), A[6]);           \
    A[7] = fmaf(sk, bf2f((u16)(ww3 >> 16)), A[7]);               \
  }

// ---- step kernel 1 ----
// E-blocks: y-chain (k-split GEMV, 8-col vectors). O-blocks: sp -> e -> softmax -> c.
// LDS: sm[0:512] vecA, sm[512:1024] vecB, sm[1024:1280] e/a (O), partials at PT.
#define PT 1536
__global__ void __launch_bounds__(512) k_step1(float* __restrict__ out, int t) {
  __shared__ __align__(16) float sm[5632];
  __shared__ float red[16];
  __shared__ float w2s[512];
  const int tid = threadIdx.x;
  const int blk = blockIdx.x;
  const int b    = ((blk >> 4) << 3) | (blk & 7);
  const int half = (blk >> 3) & 1;
  const float* scur = (t & 1) ? g_sB : g_sA;

  sm[tid] = scur[b * H_ + tid];
  if (half) w2s[tid] = bf2f(cWe2[tid]);
  __syncthreads();

  if (half == 0) {
    const int c = tid & 63, ks = tid >> 6;
    const int n0 = c << 3, kb = ks << 6;
    // ---- y1 = tanh(s@Wy1+by1): in sm[0:512] -> out sm[512:1024] ----
    {
      float a[8] = {};
      const u16* w = cWy1 + (size_t)kb * H_ + n0;
      for (int k = 0; k < 64; ++k) {
        uint4 pk = *(const uint4*)(w + (size_t)k * H_);
        float sk = sm[kb + k];
        FMA8(pk, sk, a);
      }
      float* pt = &sm[PT + ks * 512 + n0];
#pragma unroll
      for (int j = 0; j < 8; ++j) pt[j] = a[j];
    }
    __syncthreads();
    {
      float v = bf2f(cby1[tid]);
#pragma unroll
      for (int kk = 0; kk < 8; ++kk) v += sm[PT + kk * 512 + tid];
      sm[512 + tid] = ftanh(v);
    }
    __syncthreads();
    // ---- y2: in sm[512:1024] -> out sm[0:512] ----
    {
      float a[8] = {};
      const u16* w = cWy2 + (size_t)kb * H_ + n0;
      for (int k = 0; k < 64; ++k) {
        uint4 pk = *(const uint4*)(w + (size_t)k * H_);
        float sk = sm[512 + kb + k];
        FMA8(pk, sk, a);
      }
      float* pt = &sm[PT + ks * 512 + n0];
#pragma unroll
      for (int j = 0; j < 8; ++j) pt[j] = a[j];
    }
    __syncthreads();
    {
      float v = bf2f(cby2[tid]);
#pragma unroll
      for (int kk = 0; kk < 8; ++kk) v += sm[PT + kk * 512 + tid];
      sm[tid] = ftanh(v);
    }
    __syncthreads();
    // ---- y3 = y2@Wy3+by3 (N=256, 16-way k-split): in sm[0:512] ----
    {
      const int c3 = tid & 31, ks3 = tid >> 5;     // 32 col-groups, 16 k-splits
      const int m0 = c3 << 3, kb3 = ks3 << 5;      // 8 cols, 32 k's
      float a[8] = {};
      const u16* w = cWy3 + (size_t)kb3 * O_ + m0;
      for (int k = 0; k < 32; ++k) {
        uint4 pk = *(const uint4*)(w + (size_t)k * O_);
        float sk = sm[kb3 + k];
        FMA8(pk, sk, a);
      }
      float* pt = &sm[PT + ks3 * 256 + m0];
#pragma unroll
      for (int j = 0; j < 8; ++j) pt[j] = a[j];
    }
    __syncthreads();
    if (tid < O_) {
      float v = bf2f(cby3[tid]);
#pragma unroll
      for (int kk = 0; kk < 16; ++kk) v += sm[PT + kk * 256 + tid];
      out[((size_t)b * T_ + t) * O_ + tid] = v;   // fp32 store
      u16 hi = f2bf(v);
      g_abh[(size_t)b * AW + tid] = hi;
      g_abl[(size_t)b * AW + tid] = f2bf(v - bf2f(hi));
    }
  } else {
    const int c = tid & 63, ks = tid >> 6;
    const int n0 = c << 3, kb = ks << 6;
    // ---- sp = s@We1[H:]+be1: in sm[0:512] -> out sm[512:1024] ----
    {
      float a[8] = {};
      const u16* w = cWe1 + (size_t)(H_ + kb) * H_ + n0;
      for (int k = 0; k < 64; ++k) {
        uint4 pk = *(const uint4*)(w + (size_t)k * H_);
        float sk = sm[kb + k];
        FMA8(pk, sk, a);
      }
      float* pt = &sm[PT + ks * 512 + n0];
#pragma unroll
      for (int j = 0; j < 8; ++j) pt[j] = a[j];
    }
    __syncthreads();
    {
      float v = bf2f(cbe1[tid]);
#pragma unroll
      for (int kk = 0; kk < 8; ++kk) v += sm[PT + kk * 512 + tid];
      sm[512 + tid] = v;
    }
    __syncthreads();
    const int wv = tid >> 6, ln = tid & 63;
    // ---- e[tp] = sum tanh(hp+sp)*We2 ----
    {
      const float* spb = &sm[512 + (ln << 3)];
      const float* w2b = &w2s[ln << 3];
      for (int tp = wv; tp < T_; tp += 8) {
        const u16* hpp = g_hp + ((size_t)(b * T_ + tp) << 9) + (ln << 3);
        uint4 pk = *(const uint4*)hpp;
        u32 ww[4] = {pk.x, pk.y, pk.z, pk.w};
        float part = 0.f;
#pragma unroll
        for (int jj = 0; jj < 4; ++jj) {
          float lo = bf2f((u16)(ww[jj] & 0xffffu));
          float hi = bf2f((u16)(ww[jj] >> 16));
          float a0 = fminf((lo + spb[2 * jj]) * TWOLOG2E_F, 80.f);
          float a1 = fminf((hi + spb[2 * jj + 1]) * TWOLOG2E_F, 80.f);
          float z0 = EXP2(a0), z1 = EXP2(a1);
          float t0 = (z0 - 1.f) * RCPF(z0 + 1.f);
          float t1 = (z1 - 1.f) * RCPF(z1 + 1.f);
          part = fmaf(t0, w2b[2 * jj], part);
          part = fmaf(t1, w2b[2 * jj + 1], part);
        }
#pragma unroll
        for (int off = 32; off > 0; off >>= 1) part += __shfl_down(part, off, 64);
        if (ln == 0) sm[1024 + tp] = part;
      }
    }
    __syncthreads();
    // ---- softmax ----
    float v = (tid < T_) ? sm[1024 + tid] : -3.0e38f;
    float m = v;
#pragma unroll
    for (int off = 32; off > 0; off >>= 1) m = fmaxf(m, __shfl_xor(m, off, 64));
    if (ln == 0) red[wv] = m;
    __syncthreads();
    m = fmaxf(fmaxf(fmaxf(red[0], red[1]), fmaxf(red[2], red[3])),
              fmaxf(fmaxf(red[4], red[5]), fmaxf(red[6], red[7])));
    float pe = (tid < T_) ? EXP2((v - m) * LOG2E_F) : 0.f;
    float ssum = pe;
#pragma unroll
    for (int off = 32; off > 0; off >>= 1) ssum += __shfl_xor(ssum, off, 64);
    if (ln == 0) red[8 + wv] = ssum;
    __syncthreads();
    float tot = (red[8] + red[9]) + (red[10] + red[11]) +
                (red[12] + red[13]) + (red[14] + red[15]);
    float ainv = RCPF(tot);
    if (tid < T_) sm[1024 + tid] = pe * ainv;
    __syncthreads();
    // ---- c = a @ h (8 tp-splits, 8-col vectors) ----
    {
      const int ts = tid >> 6;
      float a[8] = {};
      const u16* hb = g_hb + (size_t)b * T_ * H_ + n0;
      for (int tp = ts * 32; tp < ts * 32 + 32; ++tp) {
        uint4 pk = *(const uint4*)(hb + (size_t)tp * H_);
        float av = sm[1024 + tp];
        FMA8(pk, av, a);
      }
      float* pt = &sm[PT + ts * 512 + n0];
#pragma unroll
      for (int j = 0; j < 8; ++j) pt[j] = a[j];
    }
    __syncthreads();
    {
      float v2 = 0.f;
#pragma unroll
      for (int kk = 0; kk < 8; ++kk) v2 += sm[PT + kk * 512 + tid];
      u16 hi = f2bf(v2);
      g_abh[(size_t)b * AW + O_ + tid] = hi;
      g_abl[(size_t)b * AW + O_ + tid] = f2bf(v2 - bf2f(hi));
    }
  }
}

// ---- gate kernel R,U: [128,1280]@[1280,1024] via MFMA, 8-wave K-split ----
// A = [x | s] (bf16 hi+lo), B = W_BT^T. Epilogue: sigmoid; r*s -> A cols 1280+,
// u -> g_u.
__global__ void __launch_bounds__(512) k_gates_ru(int t) {
  __shared__ float red[8 * 16 * 32];   // 16 KB
  const int tid = threadIdx.x;
  const int l = tid & 63, w = tid >> 6;
  const int mb = blockIdx.x >> 5, nb = blockIdx.x & 31;
  const int m0 = mb << 4, n0 = nb << 5;
  const int r16 = l & 15, kg = l >> 4;
  f32x4 acc0 = {0.f, 0.f, 0.f, 0.f}, acc1 = {0.f, 0.f, 0.f, 0.f};
  const size_t abase = (size_t)(m0 + r16) * AW + w * 160 + kg * 8;
  const u16* pah = g_abh + abase;
  const u16* pal = g_abl + abase;
  const u16* pb0 = W_BT + (size_t)(n0 + r16) * 1280 + w * 160 + kg * 8;
  const u16* pb1 = pb0 + (size_t)16 * 1280;
#pragma unroll
  for (int kk = 0; kk < 5; ++kk) {
    short8 ah = *(const short8*)(pah + kk * 32);
    short8 al = *(const short8*)(pal + kk * 32);
    short8 b0 = *(const short8*)(pb0 + kk * 32);
    short8 b1 = *(const short8*)(pb1 + kk * 32);
    acc0 = __builtin_amdgcn_mfma_f32_16x16x32_bf16(ah, b0, acc0, 0, 0, 0);
    acc1 = __builtin_amdgcn_mfma_f32_16x16x32_bf16(ah, b1, acc1, 0, 0, 0);
    acc0 = __builtin_amdgcn_mfma_f32_16x16x32_bf16(al, b0, acc0, 0, 0, 0);
    acc1 = __builtin_amdgcn_mfma_f32_16x16x32_bf16(al, b1, acc1, 0, 0, 0);
  }
  {
    float* pw = red + w * 512;
#pragma unroll
    for (int r = 0; r < 4; ++r) {
      int rr = kg * 4 + r;           // C/D: row = (lane>>4)*4 + reg, col = lane&15
      pw[rr * 32 + r16] = acc0[r];
      pw[rr * 32 + 16 + r16] = acc1[r];
    }
  }
  __syncthreads();
  {
    const int rr = tid >> 5, cc = tid & 31;
    float v = 0.f;
#pragma unroll
    for (int ww = 0; ww < 8; ++ww) v += red[ww * 512 + rr * 32 + cc];
    const int b = m0 + rr, cg = n0 + cc;
    const float* scur = (t & 1) ? g_sB : g_sA;
    if (cg < 512) {
      v += bf2f(cbr[cg]);
      float rv = fsigm(v);
      float rs = rv * scur[b * H_ + cg];
      u16 hi = f2bf(rs);
      g_abh[(size_t)b * AW + 1280 + cg] = hi;
      g_abl[(size_t)b * AW + 1280 + cg] = f2bf(rs - bf2f(hi));
    } else {
      int n = cg - 512;
      v += bf2f(cbu[n]);
      g_u[b * H_ + n] = fsigm(v);
    }
  }
}

// ---- gate kernel Hc + s-update: [128,1280]@[1280,512] via MFMA ----
// A2 = [x | r*s] (logical k: [0,768) -> buf col k; [768,1280) -> buf col k+512)
__global__ void __launch_bounds__(512) k_gates_h(int t) {
  __shared__ float red[8 * 16 * 16];   // 8 KB
  const int tid = threadIdx.x;
  const int l = tid & 63, w = tid >> 6;
  const int mb = blockIdx.x >> 5, nb = blockIdx.x & 31;
  const int m0 = mb << 4, n0 = nb << 4;
  const int r16 = l & 15, kg = l >> 4;
  f32x4 acc = {0.f, 0.f, 0.f, 0.f};
  const size_t arow = (size_t)(m0 + r16) * AW;
  const u16* pb = W_CT + (size_t)(n0 + r16) * 1280 + w * 160 + kg * 8;
#pragma unroll
  for (int kk = 0; kk < 5; ++kk) {
    int kc = w * 160 + kk * 32 + kg * 8;          // logical k, chunk never straddles 768
    int bc = kc + ((kc >= 768) ? 512 : 0);        // buffer col
    short8 ah = *(const short8*)(g_abh + arow + bc);
    short8 al = *(const short8*)(g_abl + arow + bc);
    short8 bb = *(const short8*)(pb + kk * 32);
    acc = __builtin_amdgcn_mfma_f32_16x16x32_bf16(ah, bb, acc, 0, 0, 0);
    acc = __builtin_amdgcn_mfma_f32_16x16x32_bf16(al, bb, acc, 0, 0, 0);
  }
  {
    float* pw = red + w * 256;
#pragma unroll
    for (int r = 0; r < 4; ++r) pw[(kg * 4 + r) * 16 + r16] = acc[r];
  }
  __syncthreads();
  if (tid < 256) {
    const int rr = tid >> 4, cc = tid & 15;
    float v = 0.f;
#pragma unroll
    for (int ww = 0; ww < 8; ++ww) v += red[ww * 256 + rr * 16 + cc];
    const int b = m0 + rr, n = n0 + cc;
    const float* scur = (t & 1) ? g_sB : g_sA;
    float* snxt       = (t & 1) ? g_sA : g_sB;
    float hc = ftanh(v);
    int idx = b * H_ + n;
    float uu = g_u[idx];
    float sn = (1.f - uu) * hc + uu * scur[idx];
    snxt[idx] = sn;
    u16 hi = f2bf(sn);
    g_abh[(size_t)b * AW + 768 + n] = hi;
    g_abl[(size_t)b * AW + 768 + n] = f2bf(sn - bf2f(hi));
  }
}

extern "C" void kernel_launch(void* const* d_in, const int* in_sizes, int n_in,
                              void* d_out, int out_size, void* d_ws, size_t ws_size,
                              hipStream_t stream) {
  (void)in_sizes; (void)n_in; (void)out_size; (void)d_ws; (void)ws_size;
  const float* h  = (const float*)d_in[0];
  float* out = (float*)d_out;

#define CONV(NAME, IDX, N) \
  hipLaunchKernelGGL(conv_##NAME, dim3(((N) + 255) / 256), dim3(256), 0, stream, \
                     (const float*)d_in[IDX])
  CONV(Wy1, 2, H_ * H_);
  CONV(by1, 3, H_);
  CONV(Wy2, 4, H_ * H_);
  CONV(by2, 5, H_);
  CONV(Wy3, 6, H_ * O_);
  CONV(by3, 7, O_);
  CONV(We1, 8, 2 * H_ * H_);
  CONV(be1, 9, H_);
  CONV(We2, 10, H_);
  // d_in[11] = be2: softmax shift-invariant, unused
  CONV(br, 14, H_);
  CONV(bu, 17, H_);
#undef CONV
  hipLaunchKernelGGL(conv_WBT, dim3((1024 * 160) / 256), dim3(256), 0, stream,
                     (const float*)d_in[12], (const float*)d_in[13],
                     (const float*)d_in[15], (const float*)d_in[16]);
  hipLaunchKernelGGL(conv_WCT, dim3((512 * 160) / 256), dim3(256), 0, stream,
                     (const float*)d_in[18], (const float*)d_in[19]);
  hipLaunchKernelGGL(conv_h, dim3((B_ * T_ * H_) / 256), dim3(256), 0, stream, h);
  hipLaunchKernelGGL(init_kernel, dim3(256), dim3(256), 0, stream,
                     (const float*)d_in[1]);
  hipLaunchKernelGGL(hproj_kernel, dim3(8, 512), dim3(256), 0, stream, h,
                     (const float*)d_in[8]);

  for (int t = 0; t < T_; ++t) {
    hipLaunchKernelGGL(k_step1, dim3(256), dim3(512), 0, stream, out, t);
    hipLaunchKernelGGL(k_gates_ru, dim3(256), dim3(512), 0, stream, t);
    hipLaunchKernelGGL(k_gates_h, dim3(256), dim3(512), 0, stream, t);
  }
}

// Round 2
// 10016.422 us; speedup vs baseline: 2.1996x; 1.3423x over previous
//
#include <hip/hip_runtime.h>

#define B_ 128
#define T_ 256
#define H_ 512
#define O_ 256
#define X_ 768

typedef unsigned short u16;
typedef unsigned int u32;

#if __has_builtin(__builtin_amdgcn_exp2f)
#define EXP2(x) __builtin_amdgcn_exp2f(x)
#else
#define EXP2(x) exp2f(x)
#endif
#if __has_builtin(__builtin_amdgcn_rcpf)
#define RCPF(x) __builtin_amdgcn_rcpf(x)
#else
#define RCPF(x) (1.0f / (x))
#endif

#define LOG2E_F 1.4426950408889634f
#define TWOLOG2E_F 2.8853900817779268f

typedef __attribute__((ext_vector_type(8))) short short8;
typedef __attribute__((ext_vector_type(4))) float f32x4;

__device__ __forceinline__ float bf2f(u16 v) {
  union { u32 u; float f; } c; c.u = ((u32)v) << 16; return c.f;
}
__device__ __forceinline__ u16 f2bf(float f) {
  union { float f; u32 u; } c; c.f = f;
  return (u16)((c.u + 0x7FFFu + ((c.u >> 16) & 1u)) >> 16);
}
__device__ __forceinline__ float ftanh(float x) {
  x = fminf(fmaxf(x, -40.f), 40.f);
  float z = EXP2(x * TWOLOG2E_F);
  return (z - 1.0f) * RCPF(z + 1.0f);
}
__device__ __forceinline__ float fsigm(float x) {
  x = fminf(fmaxf(x, -40.f), 40.f);
  return RCPF(1.0f + EXP2(-x * LOG2E_F));
}

// ---- module-scope scratch ----
__device__ u16 g_hp[(size_t)B_ * T_ * H_];   // bf16 h_proj
__device__ u16 g_hb[(size_t)B_ * T_ * H_];   // bf16 copy of h
__device__ float g_s[B_ * H_];               // fp32 state (single buffer)
__device__ float g_u[B_ * H_];
__device__ float g_sp[B_ * H_];              // s @ We1_s + be1
__device__ float g_z[B_ * 1024];             // RU partial (c,s contributions)
__device__ float g_p[B_ * H_];               // Hc partial (x @ Wxh)

// Fragment-packed activation buffers (bf16 hi + lo residual).
// Packed tile layout: idx = ((rt*NKT + kt)*512) + ((kg*16 + r)*8) + j
//   rt = b>>4, r = b&15, kt = col>>5, kg = (col>>3)&3, j = col&7
// Main A buffer (NKT=56): cols [0,256)=y3, [256,768)=c, [768,1280)=s, [1280,1792)=r*s
__device__ u16 g_ah[(size_t)8 * 56 * 512];
__device__ u16 g_al[(size_t)8 * 56 * 512];
// y-chain intermediates (NKT=16)
__device__ u16 g_y1h[(size_t)8 * 16 * 512];
__device__ u16 g_y1l[(size_t)8 * 16 * 512];
__device__ u16 g_y2h[(size_t)8 * 16 * 512];
__device__ u16 g_y2l[(size_t)8 * 16 * 512];

// Fragment-packed bf16 weights: B-tile layout idx = ((ntile*NKT + kt)*512 + l*8 + j)
// lane l holds W[k = kt*32 + (l>>4)*8 + j][n = ntile*16 + (l&15)]
__device__ u16 Wy1p[(size_t)32 * 16 * 512];
__device__ u16 Wy2p[(size_t)32 * 16 * 512];
__device__ u16 Wy3p[(size_t)16 * 16 * 512];
__device__ u16 We1sp[(size_t)32 * 16 * 512];
// W_BT: n [0,512)=r cols, [512,1024)=u; k-tiles 0..7=y3-k, 8..23=c-k, 24..39=s-k
__device__ u16 WBTp[(size_t)64 * 40 * 512];
// W_CT: n [0,512); k-tiles 0..23 = Wxh, 24..39 = Whh
__device__ u16 WCTp[(size_t)32 * 40 * 512];

// biases / We2 (bf16)
__device__ u16 cby1[H_];
__device__ u16 cby2[H_];
__device__ u16 cby3[O_];
__device__ u16 cbe1[H_];
__device__ u16 cWe2[H_];
__device__ u16 cbr[H_];
__device__ u16 cbu[H_];

__device__ __forceinline__ void store_packed(u16* dh, u16* dl, int nkt, int b,
                                             int col, float v) {
  u16 hi = f2bf(v);
  size_t idx = (((size_t)(b >> 4) * nkt + (col >> 5)) << 9) +
               ((((col >> 3) & 3) * 16 + (b & 15)) << 3) + (col & 7);
  dh[idx] = hi;
  dl[idx] = f2bf(v - bf2f(hi));
}

#define DEF_CONV(NAME, ARR, N)                                     \
  __global__ void conv_##NAME(const float* __restrict__ s) {       \
    int i = blockIdx.x * 256 + threadIdx.x;                        \
    if (i < (N)) ARR[i] = f2bf(s[i]);                              \
  }

DEF_CONV(by1, cby1, H_)
DEF_CONV(by2, cby2, H_)
DEF_CONV(by3, cby3, O_)
DEF_CONV(be1, cbe1, H_)
DEF_CONV(We2, cWe2, H_)
DEF_CONV(br, cbr, H_)
DEF_CONV(bu, cbu, H_)

__global__ void conv_h(const float* __restrict__ s) {
  size_t i = (size_t)blockIdx.x * 256 + threadIdx.x;
  g_hb[i] = f2bf(s[i]);
}

// ---- weight packers ----
#define DEF_PACKB(NAME, DST, NKT, SRCEXPR)                               \
  __global__ void NAME(const float* __restrict__ S0) {                   \
    int gid = blockIdx.x * 256 + threadIdx.x;                            \
    int l = gid & 63, kt = (gid >> 6) % (NKT);                           \
    int ntile = gid / (64 * (NKT));                                      \
    int n = ntile * 16 + (l & 15);                                       \
    __align__(16) u16 tmp[8];                                            \
    _Pragma("unroll")                                                    \
    for (int j = 0; j < 8; ++j) {                                        \
      int k = kt * 32 + ((l >> 4) << 3) + j;                             \
      tmp[j] = f2bf(SRCEXPR);                                            \
    }                                                                    \
    *(uint4*)(DST + (size_t)gid * 8) = *(const uint4*)tmp;               \
  }

DEF_PACKB(pack_Wy1, Wy1p, 16, S0[(size_t)k * 512 + n])
DEF_PACKB(pack_Wy2, Wy2p, 16, S0[(size_t)k * 512 + n])
DEF_PACKB(pack_Wy3, Wy3p, 16, S0[(size_t)k * 256 + n])
DEF_PACKB(pack_We1s, We1sp, 16, S0[(size_t)(512 + k) * 512 + n])

__global__ void pack_WBT(const float* __restrict__ Wxr, const float* __restrict__ Whr,
                         const float* __restrict__ Wxu, const float* __restrict__ Whu) {
  int gid = blockIdx.x * 256 + threadIdx.x;   // 64 ntiles * 40 kt * 64 lanes
  int l = gid & 63, kt = (gid >> 6) % 40;
  int ntile = gid / (64 * 40);
  int n = ntile * 16 + (l & 15);
  int nn = n & 511;
  __align__(16) u16 tmp[8];
#pragma unroll
  for (int j = 0; j < 8; ++j) {
    int k = kt * 32 + ((l >> 4) << 3) + j;     // 0..1279: [x | s]
    float v;
    if (n < 512) v = (k < 768) ? Wxr[(size_t)k * 512 + nn] : Whr[(size_t)(k - 768) * 512 + nn];
    else         v = (k < 768) ? Wxu[(size_t)k * 512 + nn] : Whu[(size_t)(k - 768) * 512 + nn];
    tmp[j] = f2bf(v);
  }
  *(uint4*)(WBTp + (size_t)gid * 8) = *(const uint4*)tmp;
}

__global__ void pack_WCT(const float* __restrict__ Wxh, const float* __restrict__ Whh) {
  int gid = blockIdx.x * 256 + threadIdx.x;   // 32 ntiles * 40 kt * 64
  int l = gid & 63, kt = (gid >> 6) % 40;
  int ntile = gid / (64 * 40);
  int n = ntile * 16 + (l & 15);
  __align__(16) u16 tmp[8];
#pragma unroll
  for (int j = 0; j < 8; ++j) {
    int k = kt * 32 + ((l >> 4) << 3) + j;
    float v = (k < 768) ? Wxh[(size_t)k * 512 + n] : Whh[(size_t)(k - 768) * 512 + n];
    tmp[j] = f2bf(v);
  }
  *(uint4*)(WCTp + (size_t)gid * 8) = *(const uint4*)tmp;
}

__global__ void init_kernel(const float* __restrict__ s0) {
  int g = blockIdx.x * blockDim.x + threadIdx.x;
  if (g < B_ * H_) {
    float v = s0[g];
    g_s[g] = v;
    int b = g >> 9, n = g & 511;
    store_packed(g_ah, g_al, 56, b, 768 + n, v);
  }
}

// ---- h_proj = h @ We1[:H]  (fp32 in, bf16 out) ----
__global__ void __launch_bounds__(256) hproj_kernel(const float* __restrict__ hh,
                                                    const float* __restrict__ We1) {
  __shared__ float Ast[32][72];
  __shared__ float Bs[32][72];
  const int tid = threadIdx.x;
  const int tx = tid & 15, ty = tid >> 4;
  const int n0 = blockIdx.x << 6;
  const int m0 = blockIdx.y << 6;
  float acc[4][4] = {};
  for (int k0 = 0; k0 < H_; k0 += 32) {
    {
      int row = tid >> 2, kq = (tid & 3) << 3;
      const float* src = hh + (size_t)(m0 + row) * H_ + k0 + kq;
      float4 v0 = *(const float4*)src;
      float4 v1 = *(const float4*)(src + 4);
      Ast[kq + 0][row] = v0.x; Ast[kq + 1][row] = v0.y;
      Ast[kq + 2][row] = v0.z; Ast[kq + 3][row] = v0.w;
      Ast[kq + 4][row] = v1.x; Ast[kq + 5][row] = v1.y;
      Ast[kq + 6][row] = v1.z; Ast[kq + 7][row] = v1.w;
    }
    {
      int kr = tid >> 3, nq = (tid & 7) << 3;
      const float* src = We1 + (size_t)(k0 + kr) * H_ + n0 + nq;
      float4 v0 = *(const float4*)src;
      float4 v1 = *(const float4*)(src + 4);
      float* d = &Bs[kr][nq];
      d[0] = v0.x; d[1] = v0.y; d[2] = v0.z; d[3] = v0.w;
      d[4] = v1.x; d[5] = v1.y; d[6] = v1.z; d[7] = v1.w;
    }
    __syncthreads();
#pragma unroll
    for (int kk = 0; kk < 32; ++kk) {
      const float4 a4 = *(const float4*)&Ast[kk][ty << 2];
      const float4 b4 = *(const float4*)&Bs[kk][tx << 2];
      float av[4] = {a4.x, a4.y, a4.z, a4.w};
      float bv[4] = {b4.x, b4.y, b4.z, b4.w};
#pragma unroll
      for (int i = 0; i < 4; ++i)
#pragma unroll
        for (int j = 0; j < 4; ++j) acc[i][j] = fmaf(av[i], bv[j], acc[i][j]);
    }
    __syncthreads();
  }
#pragma unroll
  for (int i = 0; i < 4; ++i) {
    u16* dst = g_hp + (size_t)(m0 + ty * 4 + i) * H_ + n0 + tx * 4;
    u32 w0 = (u32)f2bf(acc[i][0]) | ((u32)f2bf(acc[i][1]) << 16);
    u32 w1 = (u32)f2bf(acc[i][2]) | ((u32)f2bf(acc[i][3]) << 16);
    *(u32*)dst = w0;
    *(u32*)(dst + 2) = w1;
  }
}

// unpack 8 bf16 (uint4) + fma against broadcast scalar
#define FMA8(pk, sk, A)                                          \
  {                                                              \
    u32 ww0 = pk.x, ww1 = pk.y, ww2 = pk.z, ww3 = pk.w;          \
    A[0] = fmaf(sk, bf2f((u16)(ww0 & 0xffffu)), A[0]);           \
    A[1] = fmaf(sk, bf2f((u16)(ww0 >> 16)), A[1]);               \
    A[2] = fmaf(sk, bf2f((u16)(ww1 & 0xffffu)), A[2]);           \
    A[3] = fmaf(sk, bf2f((u16)(ww1 >> 16)), A[3]);               \
    A[4] = fmaf(sk, bf2f((u16)(ww2 & 0xffffu)), A[4]);           \
    A[5] = fmaf(sk, bf2f((u16)(ww2 >> 16)), A[5]);               \
    A[6] = fmaf(sk, bf2f((u16)(ww3 & 0xffffu)), A[6]);           \
    A[7] = fmaf(sk, bf2f((u16)(ww3 >> 16)), A[7]);               \
  }

// ---- GEMM core: M=16 (mt), N=64 (nb, 4 ntiles), 8-wave k-split, hi/lo A ----
template <int NKT_A, int KTA0, int NKT_B, int KTB0, int KTW>
__device__ __forceinline__ void gemm_core(const u16* __restrict__ AH,
                                          const u16* __restrict__ AL,
                                          const u16* __restrict__ BP,
                                          int mt, int nb, int tid, float* smem) {
  const int l = tid & 63, w = tid >> 6;
  f32x4 acc0 = {0.f, 0.f, 0.f, 0.f}, acc1 = {0.f, 0.f, 0.f, 0.f};
  f32x4 acc2 = {0.f, 0.f, 0.f, 0.f}, acc3 = {0.f, 0.f, 0.f, 0.f};
  const size_t abase = (((size_t)mt * NKT_A + KTA0 + w * KTW) << 9) + l * 8;
#pragma unroll
  for (int kk = 0; kk < KTW; ++kk) {
    short8 ah = *(const short8*)(AH + abase + (size_t)kk * 512);
    short8 al = *(const short8*)(AL + abase + (size_t)kk * 512);
    const size_t bbase =
        (((size_t)(nb * 4) * NKT_B + KTB0 + w * KTW + kk) << 9) + l * 8;
    short8 b0 = *(const short8*)(BP + bbase);
    short8 b1 = *(const short8*)(BP + bbase + ((size_t)NKT_B << 9));
    short8 b2 = *(const short8*)(BP + bbase + ((size_t)2 * NKT_B << 9));
    short8 b3 = *(const short8*)(BP + bbase + ((size_t)3 * NKT_B << 9));
    acc0 = __builtin_amdgcn_mfma_f32_16x16x32_bf16(ah, b0, acc0, 0, 0, 0);
    acc0 = __builtin_amdgcn_mfma_f32_16x16x32_bf16(al, b0, acc0, 0, 0, 0);
    acc1 = __builtin_amdgcn_mfma_f32_16x16x32_bf16(ah, b1, acc1, 0, 0, 0);
    acc1 = __builtin_amdgcn_mfma_f32_16x16x32_bf16(al, b1, acc1, 0, 0, 0);
    acc2 = __builtin_amdgcn_mfma_f32_16x16x32_bf16(ah, b2, acc2, 0, 0, 0);
    acc2 = __builtin_amdgcn_mfma_f32_16x16x32_bf16(al, b2, acc2, 0, 0, 0);
    acc3 = __builtin_amdgcn_mfma_f32_16x16x32_bf16(ah, b3, acc3, 0, 0, 0);
    acc3 = __builtin_amdgcn_mfma_f32_16x16x32_bf16(al, b3, acc3, 0, 0, 0);
  }
  // C/D layout: col = lane&15, row = (lane>>4)*4 + reg
  float* pw = smem + w * 1024;
  const int r0 = (l >> 4) * 4, c0 = l & 15;
#pragma unroll
  for (int r = 0; r < 4; ++r) {
    pw[(r0 + r) * 64 + 0 + c0] = acc0[r];
    pw[(r0 + r) * 64 + 16 + c0] = acc1[r];
    pw[(r0 + r) * 64 + 32 + c0] = acc2[r];
    pw[(r0 + r) * 64 + 48 + c0] = acc3[r];
  }
  __syncthreads();
}

#define EPI_V(row, col)                                              \
  float v = 0.f;                                                     \
  _Pragma("unroll") for (int ww = 0; ww < 8; ++ww)                   \
      v += smem[ww * 1024 + (row) * 64 + (col)];

// ---- k1: y1 = tanh(s@Wy1+by1)  ||  sp = s@We1_s + be1 ----
__global__ void __launch_bounds__(512) k_y1sp() {
  __shared__ float smem[8192];
  const int tid = threadIdx.x;
  const int blk = blockIdx.x;
  if (blk < 64) {
    const int mt = blk >> 3, nb = blk & 7;
    gemm_core<56, 24, 16, 0, 2>(g_ah, g_al, Wy1p, mt, nb, tid, smem);
#pragma unroll
    for (int rep = 0; rep < 2; ++rep) {
      int idx = rep * 512 + tid, row = idx >> 6, col = idx & 63;
      EPI_V(row, col);
      int gb = mt * 16 + row, gc = nb * 64 + col;
      v += bf2f(cby1[gc]);
      store_packed(g_y1h, g_y1l, 16, gb, gc, ftanh(v));
    }
  } else {
    const int blk2 = blk - 64;
    const int mt = blk2 >> 3, nb = blk2 & 7;
    gemm_core<56, 24, 16, 0, 2>(g_ah, g_al, We1sp, mt, nb, tid, smem);
#pragma unroll
    for (int rep = 0; rep < 2; ++rep) {
      int idx = rep * 512 + tid, row = idx >> 6, col = idx & 63;
      EPI_V(row, col);
      int gb = mt * 16 + row, gc = nb * 64 + col;
      g_sp[gb * H_ + gc] = v + bf2f(cbe1[gc]);
    }
  }
}

// ---- k2: y2 = tanh(y1@Wy2+by2)  ||  attention (e, softmax, c) ----
__global__ void __launch_bounds__(512) k_attn_y2() {
  __shared__ float smem[8192];
  __shared__ float red[16];
  const int tid = threadIdx.x;
  const int blk = blockIdx.x;
  if (blk < 64) {
    const int mt = blk >> 3, nb = blk & 7;
    gemm_core<16, 0, 16, 0, 2>(g_y1h, g_y1l, Wy2p, mt, nb, tid, smem);
#pragma unroll
    for (int rep = 0; rep < 2; ++rep) {
      int idx = rep * 512 + tid, row = idx >> 6, col = idx & 63;
      EPI_V(row, col);
      int gb = mt * 16 + row, gc = nb * 64 + col;
      v += bf2f(cby2[gc]);
      store_packed(g_y2h, g_y2l, 16, gb, gc, ftanh(v));
    }
  } else {
    const int b = blk - 64;
    float* sm_e = smem + 1024;   // 256 floats
    // phase 0: (sp*2log2e, -2*w2) pairs
    {
      float spv = g_sp[b * H_ + tid];
      float w2 = bf2f(cWe2[tid]);
      smem[2 * tid] = spv * TWOLOG2E_F;
      smem[2 * tid + 1] = -2.0f * w2;
    }
    __syncthreads();
    const int wv = tid >> 6, l = tid & 63;
    const int rr = l & 15, q = l >> 4;
    // e'[tp] = sum_j (-2 w2_j) / (exp(2(hp+sp)) + 1)   (shift-invariant form)
#pragma unroll
    for (int p = 0; p < 2; ++p) {
      int tp = p * 128 + wv * 16 + rr;
      const u16* rowp = g_hp + ((size_t)(b * T_ + tp) << 9);
      float part = 0.f;
      for (int i = 0; i < 16; ++i) {
        int c0 = i * 32 + q * 8;
        uint4 pk = *(const uint4*)(rowp + c0);
        const float4* swp = reinterpret_cast<const float4*>(smem + 2 * c0);
        float4 f0 = swp[0], f1 = swp[1], f2 = swp[2], f3 = swp[3];
        u32 ww[4] = {pk.x, pk.y, pk.z, pk.w};
        {
          float h0 = bf2f((u16)(ww[0] & 0xffffu)), h1 = bf2f((u16)(ww[0] >> 16));
          float x0 = fminf(fmaf(h0, TWOLOG2E_F, f0.x), 80.f);
          float x1 = fminf(fmaf(h1, TWOLOG2E_F, f0.z), 80.f);
          part = fmaf(f0.y, RCPF(EXP2(x0) + 1.f), part);
          part = fmaf(f0.w, RCPF(EXP2(x1) + 1.f), part);
        }
        {
          float h0 = bf2f((u16)(ww[1] & 0xffffu)), h1 = bf2f((u16)(ww[1] >> 16));
          float x0 = fminf(fmaf(h0, TWOLOG2E_F, f1.x), 80.f);
          float x1 = fminf(fmaf(h1, TWOLOG2E_F, f1.z), 80.f);
          part = fmaf(f1.y, RCPF(EXP2(x0) + 1.f), part);
          part = fmaf(f1.w, RCPF(EXP2(x1) + 1.f), part);
        }
        {
          float h0 = bf2f((u16)(ww[2] & 0xffffu)), h1 = bf2f((u16)(ww[2] >> 16));
          float x0 = fminf(fmaf(h0, TWOLOG2E_F, f2.x), 80.f);
          float x1 = fminf(fmaf(h1, TWOLOG2E_F, f2.z), 80.f);
          part = fmaf(f2.y, RCPF(EXP2(x0) + 1.f), part);
          part = fmaf(f2.w, RCPF(EXP2(x1) + 1.f), part);
        }
        {
          float h0 = bf2f((u16)(ww[3] & 0xffffu)), h1 = bf2f((u16)(ww[3] >> 16));
          float x0 = fminf(fmaf(h0, TWOLOG2E_F, f3.x), 80.f);
          float x1 = fminf(fmaf(h1, TWOLOG2E_F, f3.z), 80.f);
          part = fmaf(f3.y, RCPF(EXP2(x0) + 1.f), part);
          part = fmaf(f3.w, RCPF(EXP2(x1) + 1.f), part);
        }
      }
      part += __shfl_xor(part, 16, 64);
      part += __shfl_xor(part, 32, 64);
      if (q == 0) sm_e[tp] = part;
    }
    __syncthreads();
    // softmax over sm_e[0..256)
    float v = (tid < T_) ? sm_e[tid] : -3.0e38f;
    float m = v;
#pragma unroll
    for (int off = 32; off > 0; off >>= 1) m = fmaxf(m, __shfl_xor(m, off, 64));
    if (l == 0) red[wv] = m;
    __syncthreads();
    m = fmaxf(fmaxf(fmaxf(red[0], red[1]), fmaxf(red[2], red[3])),
              fmaxf(fmaxf(red[4], red[5]), fmaxf(red[6], red[7])));
    float pe = (tid < T_) ? EXP2((v - m) * LOG2E_F) : 0.f;
    float ssum = pe;
#pragma unroll
    for (int off = 32; off > 0; off >>= 1) ssum += __shfl_xor(ssum, off, 64);
    if (l == 0) red[8 + wv] = ssum;
    __syncthreads();
    float tot = (red[8] + red[9]) + (red[10] + red[11]) +
                (red[12] + red[13]) + (red[14] + red[15]);
    float ainv = RCPF(tot);
    if (tid < T_) sm_e[tid] = pe * ainv;
    __syncthreads();
    // c = a @ h  (8 tp-splits, 8 cols per thread)
    {
      const int ts = tid >> 6, c = tid & 63, n0 = c << 3;
      float a[8] = {};
      for (int tp = ts * 32; tp < ts * 32 + 32; ++tp) {
        uint4 pk = *(const uint4*)(g_hb + ((size_t)(b * T_ + tp) << 9) + n0);
        float av = sm_e[tp];
        FMA8(pk, av, a);
      }
      float* pt = smem + 1536 + ts * 512 + n0;
#pragma unroll
      for (int j = 0; j < 8; ++j) pt[j] = a[j];
    }
    __syncthreads();
    {
      float v2 = 0.f;
#pragma unroll
      for (int kk = 0; kk < 8; ++kk) v2 += smem[1536 + kk * 512 + tid];
      store_packed(g_ah, g_al, 56, b, 256 + tid, v2);
    }
  }
}

// ---- k3: y3 = y2@Wy3+by3 (-> out, A)  ||  Z = [c|s]@W_BT[kt8..39] ----
__global__ void __launch_bounds__(512) k_y3_zcs(float* __restrict__ out, int t) {
  __shared__ float smem[8192];
  const int tid = threadIdx.x;
  const int blk = blockIdx.x;
  if (blk < 32) {
    const int mt = blk >> 2, nb = blk & 3;
    gemm_core<16, 0, 16, 0, 2>(g_y2h, g_y2l, Wy3p, mt, nb, tid, smem);
#pragma unroll
    for (int rep = 0; rep < 2; ++rep) {
      int idx = rep * 512 + tid, row = idx >> 6, col = idx & 63;
      EPI_V(row, col);
      int gb = mt * 16 + row, gc = nb * 64 + col;
      v += bf2f(cby3[gc]);
      out[((size_t)gb * T_ + t) * O_ + gc] = v;
      store_packed(g_ah, g_al, 56, gb, gc, v);
    }
  } else {
    const int blk2 = blk - 32;
    const int mt = blk2 >> 4, nb = blk2 & 15;
    gemm_core<56, 8, 40, 8, 4>(g_ah, g_al, WBTp, mt, nb, tid, smem);
#pragma unroll
    for (int rep = 0; rep < 2; ++rep) {
      int idx = rep * 512 + tid, row = idx >> 6, col = idx & 63;
      EPI_V(row, col);
      int gb = mt * 16 + row, gc = nb * 64 + col;
      g_z[gb * 1024 + gc] = v;
    }
  }
}

// ---- k4: RU = sigm(y3@W_BT[0..7] + Z + b) -> r*s, u  ||  P = x@Wxh ----
__global__ void __launch_bounds__(512) k_ru_hx() {
  __shared__ float smem[8192];
  const int tid = threadIdx.x;
  const int blk = blockIdx.x;
  if (blk < 128) {
    const int mt = blk >> 4, nb = blk & 15;
    gemm_core<56, 0, 40, 0, 1>(g_ah, g_al, WBTp, mt, nb, tid, smem);
#pragma unroll
    for (int rep = 0; rep < 2; ++rep) {
      int idx = rep * 512 + tid, row = idx >> 6, col = idx & 63;
      EPI_V(row, col);
      int gb = mt * 16 + row, gc = nb * 64 + col;
      v += g_z[gb * 1024 + gc];
      if (gc < 512) {
        v += bf2f(cbr[gc]);
        float rv = fsigm(v);
        float rs = rv * g_s[gb * H_ + gc];
        store_packed(g_ah, g_al, 56, gb, 1280 + gc, rs);
      } else {
        v += bf2f(cbu[gc - 512]);
        g_u[gb * H_ + (gc - 512)] = fsigm(v);
      }
    }
  } else {
    const int blk2 = blk - 128;
    const int mt = blk2 >> 3, nb = blk2 & 7;
    gemm_core<56, 0, 40, 0, 3>(g_ah, g_al, WCTp, mt, nb, tid, smem);
#pragma unroll
    for (int rep = 0; rep < 2; ++rep) {
      int idx = rep * 512 + tid, row = idx >> 6, col = idx & 63;
      EPI_V(row, col);
      int gb = mt * 16 + row, gc = nb * 64 + col;
      g_p[gb * H_ + gc] = v;
    }
  }
}

// ---- k5: Hc = tanh(P + rs@Whh); s = (1-u)Hc + u s ----
__global__ void __launch_bounds__(512) k_hcfin() {
  __shared__ float smem[8192];
  const int tid = threadIdx.x;
  const int blk = blockIdx.x;
  const int mt = blk >> 3, nb = blk & 7;
  gemm_core<56, 40, 40, 24, 2>(g_ah, g_al, WCTp, mt, nb, tid, smem);
#pragma unroll
  for (int rep = 0; rep < 2; ++rep) {
    int idx = rep * 512 + tid, row = idx >> 6, col = idx & 63;
    EPI_V(row, col);
    int gb = mt * 16 + row, gc = nb * 64 + col;
    int sidx = gb * H_ + gc;
    v += g_p[sidx];
    float hc = ftanh(v);
    float uu = g_u[sidx];
    float sn = (1.f - uu) * hc + uu * g_s[sidx];
    g_s[sidx] = sn;
    store_packed(g_ah, g_al, 56, gb, 768 + gc, sn);
  }
}

extern "C" void kernel_launch(void* const* d_in, const int* in_sizes, int n_in,
                              void* d_out, int out_size, void* d_ws, size_t ws_size,
                              hipStream_t stream) {
  (void)in_sizes; (void)n_in; (void)out_size; (void)d_ws; (void)ws_size;
  const float* h = (const float*)d_in[0];
  float* out = (float*)d_out;

#define CONV(NAME, IDX, N) \
  hipLaunchKernelGGL(conv_##NAME, dim3(((N) + 255) / 256), dim3(256), 0, stream, \
                     (const float*)d_in[IDX])
  CONV(by1, 3, H_);
  CONV(by2, 5, H_);
  CONV(by3, 7, O_);
  CONV(be1, 9, H_);
  CONV(We2, 10, H_);
  // d_in[11] = be2: softmax shift-invariant, unused
  CONV(br, 14, H_);
  CONV(bu, 17, H_);
#undef CONV
  hipLaunchKernelGGL(pack_Wy1, dim3(128), dim3(256), 0, stream, (const float*)d_in[2]);
  hipLaunchKernelGGL(pack_Wy2, dim3(128), dim3(256), 0, stream, (const float*)d_in[4]);
  hipLaunchKernelGGL(pack_Wy3, dim3(64), dim3(256), 0, stream, (const float*)d_in[6]);
  hipLaunchKernelGGL(pack_We1s, dim3(128), dim3(256), 0, stream, (const float*)d_in[8]);
  hipLaunchKernelGGL(pack_WBT, dim3(640), dim3(256), 0, stream,
                     (const float*)d_in[12], (const float*)d_in[13],
                     (const float*)d_in[15], (const float*)d_in[16]);
  hipLaunchKernelGGL(pack_WCT, dim3(320), dim3(256), 0, stream,
                     (const float*)d_in[18], (const float*)d_in[19]);
  hipLaunchKernelGGL(conv_h, dim3((B_ * T_ * H_) / 256), dim3(256), 0, stream, h);
  hipLaunchKernelGGL(init_kernel, dim3(256), dim3(256), 0, stream,
                     (const float*)d_in[1]);
  hipLaunchKernelGGL(hproj_kernel, dim3(8, 512), dim3(256), 0, stream, h,
                     (const float*)d_in[8]);

  for (int t = 0; t < T_; ++t) {
    hipLaunchKernelGGL(k_y1sp, dim3(128), dim3(512), 0, stream);
    hipLaunchKernelGGL(k_attn_y2, dim3(192), dim3(512), 0, stream);
    hipLaunchKernelGGL(k_y3_zcs, dim3(160), dim3(512), 0, stream, out, t);
    hipLaunchKernelGGL(k_ru_hx, dim3(192), dim3(512), 0, stream);
    hipLaunchKernelGGL(k_hcfin, dim3(64), dim3(512), 0, stream);
  }
}